// Round 7
// baseline (795.253 us; speedup 1.0000x reference)
//
#include <hip/hip_runtime.h>

namespace {
constexpr int kB = 32;       // batch
constexpr int kN = 32768;    // num_primary
constexpr int kQ = 8;        // dim_primary
constexpr int kD = 10;       // num_digit
constexpr int kV = 16;       // dim_digit
constexpr int kRows = kB * kD;        // 320
constexpr int kNT = 4;                // n per tile
constexpr int kTiles = kN / kNT;      // 8192
constexpr int kThreads = 512;         // 8 waves; wave = bgrp; lane = dslot*4+vq
constexpr int kGrid = 512;            // 2 blocks/CU; 16 tiles/block
// LDS W layout: per (n_l,d) a 576B block (36 chunks: 32 real [qh][v] + 4 pad).
// chunk(qh,v) at offset qh*256 + v*16. d-stride 576 => per-instr addresses
// (10 dd x 4 vq) spread 5-deep balanced over the 8 bank-quads.
constexpr int kWBlk = 576;
constexpr int kWReg = 23552;               // 1472 chunks = 23 wave-strips
constexpr int kBuf = kWReg;                // u no longer staged in LDS
}

__device__ __forceinline__ void g2lds16(const void* g, void* l) {
  __builtin_amdgcn_global_load_lds(
      (const __attribute__((address_space(1))) unsigned int*)g,
      (__attribute__((address_space(3))) unsigned int*)l, 16, 0, 0);
}

template <int CTRL>
__device__ __forceinline__ float dpp_mv(float x) {
  return __int_as_float(__builtin_amdgcn_update_dpp(
      0, __float_as_int(x), CTRL, 0xF, 0xF, true));
}

// Stage one tile (4 n): W region, 23 strips of 1KB. LDS dst is wave-uniform
// strip base (HW adds lane*16); global src per-lane carries the
// [v][q] -> [qh][v-chunk] permutation (16B chunks contiguous both sides).
__device__ __forceinline__ void stage_tile(const float* __restrict__ W,
                                           char* buf, int n0) {
  const int wv = threadIdx.x >> 6;
  const int ln = threadIdx.x & 63;
  #pragma unroll
  for (int k = 0; k < 3; ++k) {
    const int s = wv + 8 * k;  // wave-uniform strip id 0..23 (23 used)
    if (s < 23) {
      const int g = s * 64 + ln;        // chunk slot 0..1471
      const int blk = g / 36;           // (n_l, d) block
      const int c = g - blk * 36;       // chunk within block
      const char* src;
      if (g < 1440 && c < 32) {
        const int n_l = blk / 10, d = blk - n_l * 10;
        const int qh = c >> 4, v = c & 15;
        src = (const char*)W + ((size_t)d * kN + n0 + n_l) * 512 +
              (size_t)(v * 32 + qh * 16);
      } else {
        src = (const char*)W;  // filler into pad slots
      }
      g2lds16(src, buf + s * 1024);
    }
  }
}

// PHASE 0: c = 1/10 exactly (folded into final scale). PHASE 1: softmax(u_hat.vprev).
template <int PHASE>
__launch_bounds__(kThreads, 2)   // 2 blocks/CU -> 128-VGPR budget
__global__ void routing_pass(const float* __restrict__ u,     // [B,N,Q]
                             const float* __restrict__ W,     // [D,N,V,Q]
                             const float* __restrict__ vprev, // [B,D,V]
                             float* __restrict__ s_out) {     // [B,D,V]
  __shared__ __align__(16) char smem[2 * kBuf];
  const int t = threadIdx.x;
  // Wave-uniform b-group via readfirstlane so u loads scalarize to s_load.
  const int bgrp = __builtin_amdgcn_readfirstlane(t >> 6);
  const int ln = t & 63;
  const int dslot = ln >> 2;     // 0..15, active if <10
  const int vq = ln & 3;         // v-quarter; thread's v = j*4+vq
  const bool act = (dslot < kD);
  const int dd = act ? dslot : dslot - kD;  // idle lanes alias real rows (broadcast)
  const int b0 = bgrp * 4;

  float vp[4][4];
  if constexpr (PHASE != 0) {
    #pragma unroll
    for (int bb = 0; bb < 4; ++bb)
      #pragma unroll
      for (int j = 0; j < 4; ++j)
        vp[bb][j] = vprev[((b0 + bb) * kD + dd) * kV + j * 4 + vq];
  }

  float acc[4][4];
  #pragma unroll
  for (int bb = 0; bb < 4; ++bb)
    #pragma unroll
    for (int j = 0; j < 4; ++j) acc[bb][j] = 0.0f;

  int tile = blockIdx.x;
  int cur = 0;
  stage_tile(W, smem, tile * kNT);

  for (; tile < kTiles; tile += kGrid) {
    __syncthreads();  // drains staged loads of cur; prev reads done
    const int nxt = tile + kGrid;
    if (nxt < kTiles)
      stage_tile(W, smem + (cur ^ 1) * kBuf, nxt * kNT);

    const char* base = smem + cur * kBuf;
    #pragma unroll
    for (int nl = 0; nl < kNT; ++nl) {
      const int n = tile * kNT + nl;  // uniform
      float uh[4][4];
      #pragma unroll
      for (int bb = 0; bb < 4; ++bb)
        #pragma unroll
        for (int j = 0; j < 4; ++j) uh[bb][j] = 0.0f;
      const char* wb = base + (nl * kD + dd) * kWBlk + vq * 16;
      #pragma unroll
      for (int qh = 0; qh < 2; ++qh) {
        // u[4b][4q]: wave-uniform global loads -> SGPRs (SMEM pipe, not DS)
        float uu[4][4];
        #pragma unroll
        for (int bb = 0; bb < 4; ++bb) {
          const float4 a = *(const float4*)(
              u + ((size_t)(b0 + bb) * kN + n) * kQ + qh * 4);
          uu[bb][0] = a.x; uu[bb][1] = a.y; uu[bb][2] = a.z; uu[bb][3] = a.w;
        }
        #pragma unroll
        for (int j = 0; j < 4; ++j) {
          const float4 w4 = *(const float4*)(wb + qh * 256 + j * 64);
          #pragma unroll
          for (int bb = 0; bb < 4; ++bb) {
            uh[bb][j] = fmaf(w4.x, uu[bb][0], uh[bb][j]);
            uh[bb][j] = fmaf(w4.y, uu[bb][1], uh[bb][j]);
            uh[bb][j] = fmaf(w4.z, uu[bb][2], uh[bb][j]);
            uh[bb][j] = fmaf(w4.w, uu[bb][3], uh[bb][j]);
          }
        }
      }
      if constexpr (PHASE != 0) {
        // logits for all 4 b (vq all-reduce via quad_perm DPP: xor1, xor2)
        float lg[4];
        #pragma unroll
        for (int bb = 0; bb < 4; ++bb) {
          float t0 = uh[bb][0] * vp[bb][0];
          t0 = fmaf(uh[bb][1], vp[bb][1], t0);
          t0 = fmaf(uh[bb][2], vp[bb][2], t0);
          t0 = fmaf(uh[bb][3], vp[bb][3], t0);
          t0 += dpp_mv<0xB1>(t0);
          t0 += dpp_mv<0x4E>(t0);
          lg[bb] = t0;
        }
        // each lane takes bb = vq -> ONE exp, ONE den-reduce, ONE rcp for all 4 b
        const float ta = (vq & 2) ? lg[2] : lg[0];
        const float tb = (vq & 2) ? lg[3] : lg[1];
        const float lsel = (vq & 1) ? tb : ta;
        const float esel = act ? __expf(lsel) : 0.0f;
        float den = esel;                 // sum over 16 dslots, vq preserved:
        den += dpp_mv<0x124>(den);        // row_ror:4
        den += dpp_mv<0x128>(den);        // row_ror:8
        den += __shfl_xor(den, 16);       // cross-row (DS)
        den += __shfl_xor(den, 32);       // cross-half (DS)
        const float csel = esel * __builtin_amdgcn_rcpf(den);
        // redistribute: quad_perm broadcast of each quad lane's c
        const float cb[4] = {dpp_mv<0x00>(csel), dpp_mv<0x55>(csel),
                             dpp_mv<0xAA>(csel), dpp_mv<0xFF>(csel)};
        #pragma unroll
        for (int bb = 0; bb < 4; ++bb)
          #pragma unroll
          for (int j = 0; j < 4; ++j)
            acc[bb][j] = fmaf(cb[bb], uh[bb][j], acc[bb][j]);
      } else {
        #pragma unroll
        for (int bb = 0; bb < 4; ++bb)
          #pragma unroll
          for (int j = 0; j < 4; ++j) acc[bb][j] += uh[bb][j];
      }
    }
    cur ^= 1;
  }

  if (act) {
    const float scale = (PHASE == 0) ? 0.1f : 1.0f;
    #pragma unroll
    for (int bb = 0; bb < 4; ++bb) {
      float* srow = s_out + ((b0 + bb) * kD + dslot) * kV + vq;
      #pragma unroll
      for (int j = 0; j < 4; ++j)
        atomicAdd(&srow[j * 4], acc[bb][j] * scale);
    }
  }
}

// squash per (b,d) row. MODE 0: vprev = squash(s); s = 0
//                       MODE 1: vprev += squash(s); s = 0
//                       MODE 2: out = squash(s)
template <int MODE>
__global__ void squash_kernel(float* __restrict__ s,
                              float* __restrict__ vprev,
                              float* __restrict__ out) {
  const int t = threadIdx.x;
  if (t >= kRows) return;
  float* sr = s + t * kV;
  float sv[kV];
  float n2 = 0.0f;
  #pragma unroll
  for (int v = 0; v < kV; ++v) {
    sv[v] = sr[v];
    n2 = fmaf(sv[v], sv[v], n2);
  }
  if (MODE != 2) {
    #pragma unroll
    for (int v = 0; v < kV; ++v) sr[v] = 0.0f;  // ready for next pass
  }
  const float norm = sqrtf(n2);
  const float coef = n2 / ((n2 + 1.0f) * (norm + 1e-7f));
  float* dst = (MODE == 2) ? (out + t * kV) : (vprev + t * kV);
  #pragma unroll
  for (int v = 0; v < kV; ++v) {
    float val = coef * sv[v];
    if (MODE == 1) val += dst[v];
    dst[v] = val;
  }
}

extern "C" void kernel_launch(void* const* d_in, const int* in_sizes, int n_in,
                              void* d_out, int out_size, void* d_ws, size_t ws_size,
                              hipStream_t stream) {
  const float* u = reinterpret_cast<const float*>(d_in[0]);  // primary_caps [B,N,Q]
  const float* W = reinterpret_cast<const float*>(d_in[1]);  // W [D,N,V,Q]
  float* out = reinterpret_cast<float*>(d_out);              // v [B,D,V] fp32

  float* s = reinterpret_cast<float*>(d_ws);   // [B,D,V] accumulator
  float* vprev = s + kRows * kV;               // [B,D,V] running v / vsum
  const size_t sbytes = (size_t)kRows * kV * sizeof(float);

  // r = 0: c uniform -> s0 = 0.1 * sum_n u_hat ; v0 = squash(s0)
  (void)hipMemsetAsync(s, 0, sbytes, stream);
  routing_pass<0><<<kGrid, kThreads, 0, stream>>>(u, W, nullptr, s);
  squash_kernel<0><<<1, kThreads, 0, stream>>>(s, vprev, out);

  // r = 1: logits = u_hat . v0 ; v1 = squash(s1) ; vprev = v0 + v1
  routing_pass<1><<<kGrid, kThreads, 0, stream>>>(u, W, vprev, s);
  squash_kernel<1><<<1, kThreads, 0, stream>>>(s, vprev, out);

  // r = 2: logits = u_hat . (v0+v1) ; out = squash(s2)
  routing_pass<1><<<kGrid, kThreads, 0, stream>>>(u, W, vprev, s);
  squash_kernel<2><<<1, kThreads, 0, stream>>>(s, vprev, out);
}

// Round 8
// 592.979 us; speedup vs baseline: 1.3411x; 1.3411x over previous
//
#include <hip/hip_runtime.h>

namespace {
constexpr int kB = 32;       // batch
constexpr int kN = 32768;    // num_primary
constexpr int kQ = 8;        // dim_primary
constexpr int kD = 10;       // num_digit
constexpr int kV = 16;       // dim_digit
constexpr int kRows = kB * kD;        // 320
constexpr int kNT = 4;                // n per tile
constexpr int kTiles = kN / kNT;      // 8192
constexpr int kThreads = 512;         // 8 waves; wave = bgrp; lane = dslot*4+vq
constexpr int kGrid = 512;            // 2 blocks/CU; 16 tiles/block
// LDS W layout: per (n_l,d) a 576B block (36 chunks: 32 real [qh][v] + 4 pad).
// chunk(qh,v) at offset qh*256 + v*16. d-stride 576 => per-instr addresses
// (10 dd x 4 vq) spread 5-deep balanced over the 8 bank-quads.
constexpr int kWBlk = 576;
constexpr int kWReg = 23552;               // 1472 chunks = 23 wave-strips
constexpr int kUReg = kNT * kB * 32;       // 4096 B = 4 strips, [n_l][b][q]
constexpr int kBuf = kWReg + kUReg;        // 27648 B
}

__device__ __forceinline__ void g2lds16(const void* g, void* l) {
  __builtin_amdgcn_global_load_lds(
      (const __attribute__((address_space(1))) unsigned int*)g,
      (__attribute__((address_space(3))) unsigned int*)l, 16, 0, 0);
}

template <int CTRL>
__device__ __forceinline__ float dpp_mv(float x) {
  return __int_as_float(__builtin_amdgcn_update_dpp(
      0, __float_as_int(x), CTRL, 0xF, 0xF, true));
}

template <int LANE>
__device__ __forceinline__ float rdlane(float x) {
  return __int_as_float(__builtin_amdgcn_readlane(__float_as_int(x), LANE));
}

// Stage one tile (4 n): W region 23 strips of 1KB + u region 4 strips.
// LDS dst is wave-uniform strip base (HW adds lane*16); global src per-lane
// carries the [v][q] -> [qh][v-chunk] permutation (16B chunks contiguous both sides).
__device__ __forceinline__ void stage_tile(const float* __restrict__ u,
                                           const float* __restrict__ W,
                                           char* buf, int n0) {
  const int wv = threadIdx.x >> 6;
  const int ln = threadIdx.x & 63;
  #pragma unroll
  for (int k = 0; k < 4; ++k) {
    const int s = wv + 8 * k;  // wave-uniform strip id 0..31 (27 used)
    if (s < 23) {
      const int g = s * 64 + ln;        // chunk slot 0..1471
      const int blk = g / 36;           // (n_l, d) block
      const int c = g - blk * 36;       // chunk within block
      const char* src;
      if (g < 1440 && c < 32) {
        const int n_l = blk / 10, d = blk - n_l * 10;
        const int qh = c >> 4, v = c & 15;
        src = (const char*)W + ((size_t)d * kN + n0 + n_l) * 512 +
              (size_t)(v * 32 + qh * 16);
      } else {
        src = (const char*)W;  // filler into pad slots
      }
      g2lds16(src, buf + s * 1024);
    } else if (s < 27) {
      const int s2 = s - 23;            // 0..3: u floats [n_l][b][q]
      const int h = s2 * 64 + ln;       // 0..255
      const int n_l = h >> 6, r = h & 63, b = r >> 1, qh = r & 1;
      const char* src = (const char*)u +
          ((size_t)b * kN + n0 + n_l) * 32 + (size_t)qh * 16;
      g2lds16(src, buf + kWReg + s2 * 1024);
    }
  }
}

// PHASE 0: c = 1/10 exactly (folded into final scale). PHASE 1: softmax(u_hat.vprev).
template <int PHASE>
__launch_bounds__(kThreads, 2)   // 2 blocks/CU -> 128-VGPR budget
__global__ void routing_pass(const float* __restrict__ u,     // [B,N,Q]
                             const float* __restrict__ W,     // [D,N,V,Q]
                             const float* __restrict__ vprev, // [B,D,V]
                             float* __restrict__ s_out) {     // [B,D,V]
  __shared__ __align__(16) char smem[2 * kBuf];
  const int t = threadIdx.x;
  const int bgrp = __builtin_amdgcn_readfirstlane(t >> 6);  // wave id = b-group
  const int ln = t & 63;
  const int dslot = ln >> 2;     // 0..15, active if <10
  const int vq = ln & 3;         // v-quarter; thread's v = j*4+vq
  const bool act = (dslot < kD);
  const int dd = act ? dslot : dslot - kD;  // idle lanes alias real rows (broadcast)
  const int b0 = bgrp * 4;

  float vp[4][4];
  if constexpr (PHASE != 0) {
    #pragma unroll
    for (int bb = 0; bb < 4; ++bb)
      #pragma unroll
      for (int j = 0; j < 4; ++j)
        vp[bb][j] = vprev[((b0 + bb) * kD + dd) * kV + j * 4 + vq];
  }

  float acc[4][4];
  #pragma unroll
  for (int bb = 0; bb < 4; ++bb)
    #pragma unroll
    for (int j = 0; j < 4; ++j) acc[bb][j] = 0.0f;

  int tile = blockIdx.x;
  int cur = 0;
  stage_tile(u, W, smem, tile * kNT);

  for (; tile < kTiles; tile += kGrid) {
    __syncthreads();  // drains staged loads of cur; prev reads done
    const int nxt = tile + kGrid;
    if (nxt < kTiles)
      stage_tile(u, W, smem + (cur ^ 1) * kBuf, nxt * kNT);

    const char* base = smem + cur * kBuf;
    // Distributed u pickup: 2 ds_read_b32 cover this wave's whole tile
    // (lane l holds u[n_l = pair*2 + (l>>5)][b0 + ((l&31)>>3)][(l&7)]).
    const float* ur = (const float*)(base + kWReg);
    float ureg0 = ur[((ln >> 5) + 0) * 256 + b0 * 8 + (ln & 31)];
    float ureg1 = ur[((ln >> 5) + 2) * 256 + b0 * 8 + (ln & 31)];

    #pragma unroll
    for (int nl = 0; nl < kNT; ++nl) {
      const float upair = (nl < 2) ? ureg0 : ureg1;
      constexpr int kHB0[4] = {0, 32, 0, 32};
      const int hb = kHB0[nl];  // compile-time under unroll

      float uh[4][4];
      #pragma unroll
      for (int bb = 0; bb < 4; ++bb)
        #pragma unroll
        for (int j = 0; j < 4; ++j) uh[bb][j] = 0.0f;
      const char* wb = base + (nl * kD + dd) * kWBlk + vq * 16;
      #pragma unroll
      for (int qh = 0; qh < 2; ++qh) {
        // u values -> SGPRs via compile-time readlane (VALU, no DS traffic)
        float us[4][4];
        #pragma unroll
        for (int bb = 0; bb < 4; ++bb) {
          #pragma unroll
          for (int ql = 0; ql < 4; ++ql) {
            const int lane = hb + bb * 8 + qh * 4 + ql;
            switch (lane & 63) {  // force constant dispatch
              default: break;
            }
            us[bb][ql] = __int_as_float(__builtin_amdgcn_readlane(
                __float_as_int(upair), hb + bb * 8 + qh * 4 + ql));
          }
        }
        #pragma unroll
        for (int j = 0; j < 4; ++j) {
          const float4 w4 = *(const float4*)(wb + qh * 256 + j * 64);
          #pragma unroll
          for (int bb = 0; bb < 4; ++bb) {
            uh[bb][j] = fmaf(w4.x, us[bb][0], uh[bb][j]);
            uh[bb][j] = fmaf(w4.y, us[bb][1], uh[bb][j]);
            uh[bb][j] = fmaf(w4.z, us[bb][2], uh[bb][j]);
            uh[bb][j] = fmaf(w4.w, us[bb][3], uh[bb][j]);
          }
        }
      }
      if constexpr (PHASE != 0) {
        // logits for all 4 b (vq all-reduce via quad_perm DPP: xor1, xor2)
        float lg[4];
        #pragma unroll
        for (int bb = 0; bb < 4; ++bb) {
          float t0 = uh[bb][0] * vp[bb][0];
          t0 = fmaf(uh[bb][1], vp[bb][1], t0);
          t0 = fmaf(uh[bb][2], vp[bb][2], t0);
          t0 = fmaf(uh[bb][3], vp[bb][3], t0);
          t0 += dpp_mv<0xB1>(t0);
          t0 += dpp_mv<0x4E>(t0);
          lg[bb] = t0;
        }
        // each lane takes bb = vq -> ONE exp, ONE den-reduce, ONE rcp for all 4 b
        const float ta = (vq & 2) ? lg[2] : lg[0];
        const float tb = (vq & 2) ? lg[3] : lg[1];
        const float lsel = (vq & 1) ? tb : ta;
        const float esel = act ? __expf(lsel) : 0.0f;
        float den = esel;                 // sum over 16 dslots, vq preserved:
        den += dpp_mv<0x124>(den);        // row_ror:4
        den += dpp_mv<0x128>(den);        // row_ror:8
        den += __shfl_xor(den, 16);       // cross-row (DS)
        den += __shfl_xor(den, 32);       // cross-half (DS)
        const float csel = esel * __builtin_amdgcn_rcpf(den);
        // redistribute: quad_perm broadcast of each quad lane's c
        const float cb[4] = {dpp_mv<0x00>(csel), dpp_mv<0x55>(csel),
                             dpp_mv<0xAA>(csel), dpp_mv<0xFF>(csel)};
        #pragma unroll
        for (int bb = 0; bb < 4; ++bb)
          #pragma unroll
          for (int j = 0; j < 4; ++j)
            acc[bb][j] = fmaf(cb[bb], uh[bb][j], acc[bb][j]);
      } else {
        #pragma unroll
        for (int bb = 0; bb < 4; ++bb)
          #pragma unroll
          for (int j = 0; j < 4; ++j) acc[bb][j] += uh[bb][j];
      }
    }
    cur ^= 1;
  }

  if (act) {
    const float scale = (PHASE == 0) ? 0.1f : 1.0f;
    #pragma unroll
    for (int bb = 0; bb < 4; ++bb) {
      float* srow = s_out + ((b0 + bb) * kD + dslot) * kV + vq;
      #pragma unroll
      for (int j = 0; j < 4; ++j)
        atomicAdd(&srow[j * 4], acc[bb][j] * scale);
    }
  }
}

// squash per (b,d) row. MODE 0: vprev = squash(s); s = 0
//                       MODE 1: vprev += squash(s); s = 0
//                       MODE 2: out = squash(s)
template <int MODE>
__global__ void squash_kernel(float* __restrict__ s,
                              float* __restrict__ vprev,
                              float* __restrict__ out) {
  const int t = threadIdx.x;
  if (t >= kRows) return;
  float* sr = s + t * kV;
  float sv[kV];
  float n2 = 0.0f;
  #pragma unroll
  for (int v = 0; v < kV; ++v) {
    sv[v] = sr[v];
    n2 = fmaf(sv[v], sv[v], n2);
  }
  if (MODE != 2) {
    #pragma unroll
    for (int v = 0; v < kV; ++v) sr[v] = 0.0f;  // ready for next pass
  }
  const float norm = sqrtf(n2);
  const float coef = n2 / ((n2 + 1.0f) * (norm + 1e-7f));
  float* dst = (MODE == 2) ? (out + t * kV) : (vprev + t * kV);
  #pragma unroll
  for (int v = 0; v < kV; ++v) {
    float val = coef * sv[v];
    if (MODE == 1) val += dst[v];
    dst[v] = val;
  }
}

extern "C" void kernel_launch(void* const* d_in, const int* in_sizes, int n_in,
                              void* d_out, int out_size, void* d_ws, size_t ws_size,
                              hipStream_t stream) {
  const float* u = reinterpret_cast<const float*>(d_in[0]);  // primary_caps [B,N,Q]
  const float* W = reinterpret_cast<const float*>(d_in[1]);  // W [D,N,V,Q]
  float* out = reinterpret_cast<float*>(d_out);              // v [B,D,V] fp32

  float* s = reinterpret_cast<float*>(d_ws);   // [B,D,V] accumulator
  float* vprev = s + kRows * kV;               // [B,D,V] running v / vsum
  const size_t sbytes = (size_t)kRows * kV * sizeof(float);

  // r = 0: c uniform -> s0 = 0.1 * sum_n u_hat ; v0 = squash(s0)
  (void)hipMemsetAsync(s, 0, sbytes, stream);
  routing_pass<0><<<kGrid, kThreads, 0, stream>>>(u, W, nullptr, s);
  squash_kernel<0><<<1, kThreads, 0, stream>>>(s, vprev, out);

  // r = 1: logits = u_hat . v0 ; v1 = squash(s1) ; vprev = v0 + v1
  routing_pass<1><<<kGrid, kThreads, 0, stream>>>(u, W, vprev, s);
  squash_kernel<1><<<1, kThreads, 0, stream>>>(s, vprev, out);

  // r = 2: logits = u_hat . (v0+v1) ; out = squash(s2)
  routing_pass<1><<<kGrid, kThreads, 0, stream>>>(u, W, vprev, s);
  squash_kernel<2><<<1, kThreads, 0, stream>>>(s, vprev, out);
}